// Round 1
// baseline (1054.768 us; speedup 1.0000x reference)
//
#include <hip/hip_runtime.h>
#include <math.h>

// Problem constants (fixed by the reference):
#define B_ 4
#define C_ 192
#define L_ 4096
#define CO_ 64

// Workspace layout (fp32): f | g | h | v1, each B_*CO_*L_ floats (4 MB).
// Requires ws_size >= 16 MB. All of it is fully rewritten by proj_kernel
// every launch, so the harness's 0xAA poison is harmless.

// ---------------------------------------------------------------------------
// Kernel 1: the four 1x1-conv projections.  Y[p][o][l] = sum_c W_p[o][c] x[c][l]
// Grid: (L_/64, B_), block 256.  Wave w (0..3) handles projection p=w entirely
// (64 output rows), lanes are 64 consecutive l values.  x tile staged in LDS,
// W rows streamed as float4 (L2-resident, wave-uniform -> broadcast).
// ---------------------------------------------------------------------------
__global__ __launch_bounds__(256) void proj_kernel(
    const float* __restrict__ x,
    const float* __restrict__ Wq, const float* __restrict__ Wk,
    const float* __restrict__ Wv, const float* __restrict__ Wv1,
    float* __restrict__ ws) {
  __shared__ float xl[C_][64];
  const int b = blockIdx.y;
  const int l0 = blockIdx.x * 64;
  const int t = threadIdx.x;
  const int lane = t & 63;
  const int w = t >> 6;

  const float* xb = x + (size_t)b * C_ * L_ + l0;
  for (int i = t; i < C_ * 64; i += 256) {
    const int c = i >> 6, l = i & 63;
    xl[c][l] = xb[(size_t)c * L_ + l];
  }
  __syncthreads();

  const float* W = (w == 0) ? Wq : (w == 1) ? Wk : (w == 2) ? Wv : Wv1;
  float acc[CO_];
#pragma unroll
  for (int o = 0; o < CO_; ++o) acc[o] = 0.f;

  for (int c = 0; c < C_; c += 4) {
    const float x0 = xl[c + 0][lane];
    const float x1 = xl[c + 1][lane];
    const float x2 = xl[c + 2][lane];
    const float x3 = xl[c + 3][lane];
#pragma unroll
    for (int o = 0; o < CO_; ++o) {
      const float4 wv = *(const float4*)(W + o * C_ + c);
      acc[o] += wv.x * x0 + wv.y * x1 + wv.z * x2 + wv.w * x3;
    }
  }

  float* dst = ws + (size_t)w * ((size_t)B_ * CO_ * L_) +
               (size_t)b * CO_ * L_ + l0;
#pragma unroll
  for (int o = 0; o < CO_; ++o) dst[(size_t)o * L_ + lane] = acc[o];
}

// ---------------------------------------------------------------------------
// Kernel 2: flash-style attention over l (softmax axis), fp32.
// Grid: (L_/64 m-tiles, B_), block 256 = 4 waves.
// Thread t: owns output column m = m0 + (t&63); slice s = t>>6 processes the
// l-quarter [s*16, s*16+16) of each 64-l staged tile with its own online
// (mx, Z, oacc[64]) state; the 4 slices are merged at the end via LDS.
// fT/hT staged as [l][o] with row stride 68 (272 B: 16B-aligned rows,
// wave-uniform broadcast ds_read_b128 in the inner loops).
// ---------------------------------------------------------------------------
__global__ __launch_bounds__(256) void attn_kernel(
    const float* __restrict__ ws, const float* __restrict__ gamma_p,
    float* __restrict__ out) {
  __shared__ float fT[64][68];
  __shared__ float hT[64][68];
  __shared__ float obuf[64][68];
  __shared__ float redA[4][64];
  __shared__ float redB[4][64];

  const int b = blockIdx.y;
  const int m0 = blockIdx.x * 64;
  const int t = threadIdx.x;
  const int lane = t & 63;  // m within tile (compute) / l within tile (staging)
  const int s = t >> 6;     // wave id = l-slice

  const size_t NB = (size_t)B_ * CO_ * L_;
  const float* f = ws;
  const float* g = ws + NB;
  const float* h = ws + 2 * NB;
  const float* v1 = ws + 3 * NB;
  const float* fb = f + (size_t)b * CO_ * L_;
  const float* hb = h + (size_t)b * CO_ * L_;
  const float* gb = g + (size_t)b * CO_ * L_ + m0;

  // query for my column m: q[o] = g[b][o][m0+lane]
  float q[CO_];
#pragma unroll
  for (int o = 0; o < CO_; ++o) q[o] = gb[(size_t)o * L_ + lane];

  float oacc[CO_];
#pragma unroll
  for (int o = 0; o < CO_; ++o) oacc[o] = 0.f;
  float mx = -INFINITY, Z = 0.f;

  for (int lt = 0; lt < L_ / 64; ++lt) {
    __syncthreads();  // protect fT/hT from overwrite while laggards compute
    {
      const int lg = lt * 64 + lane;
#pragma unroll
      for (int i = 0; i < 16; ++i) {
        const int o = s * 16 + i;
        fT[lane][o] = fb[(size_t)o * L_ + lg];
        hT[lane][o] = hb[(size_t)o * L_ + lg];
      }
    }
    __syncthreads();

#pragma unroll
    for (int half = 0; half < 2; ++half) {
      const int lbase = s * 16 + half * 8;
      // scores for my 8 l values: sc[j] = sum_o q[o] * f[o][lbase+j]
      float sc[8];
#pragma unroll
      for (int j = 0; j < 8; ++j) sc[j] = 0.f;
#pragma unroll
      for (int og = 0; og < 16; ++og) {
        const float q0 = q[og * 4 + 0], q1 = q[og * 4 + 1];
        const float q2 = q[og * 4 + 2], q3 = q[og * 4 + 3];
#pragma unroll
        for (int j = 0; j < 8; ++j) {
          const float4 fv = *(const float4*)&fT[lbase + j][og * 4];
          sc[j] += q0 * fv.x + q1 * fv.y + q2 * fv.z + q3 * fv.w;
        }
      }
      // online softmax update
      float tmax = sc[0];
#pragma unroll
      for (int j = 1; j < 8; ++j) tmax = fmaxf(tmax, sc[j]);
      const float mnew = fmaxf(mx, tmax);
      const float corr = __expf(mx - mnew);  // exp(-inf)=0 handles first tile
      Z *= corr;
#pragma unroll
      for (int o = 0; o < CO_; ++o) oacc[o] *= corr;
      mx = mnew;
      float wgt[8];
#pragma unroll
      for (int j = 0; j < 8; ++j) {
        wgt[j] = __expf(sc[j] - mx);
        Z += wgt[j];
      }
      // oacc[o] += sum_j wgt[j] * h[o][lbase+j]
#pragma unroll
      for (int og = 0; og < 16; ++og) {
        float a0 = oacc[og * 4 + 0], a1 = oacc[og * 4 + 1];
        float a2 = oacc[og * 4 + 2], a3 = oacc[og * 4 + 3];
#pragma unroll
        for (int j = 0; j < 8; ++j) {
          const float4 hv = *(const float4*)&hT[lbase + j][og * 4];
          a0 += wgt[j] * hv.x;
          a1 += wgt[j] * hv.y;
          a2 += wgt[j] * hv.z;
          a3 += wgt[j] * hv.w;
        }
        oacc[og * 4 + 0] = a0;
        oacc[og * 4 + 1] = a1;
        oacc[og * 4 + 2] = a2;
        oacc[og * 4 + 3] = a3;
      }
    }
  }

  // ---- merge the 4 l-slices (per m column) ----
  redA[s][lane] = mx;
  __syncthreads();
  const float M = fmaxf(fmaxf(redA[0][lane], redA[1][lane]),
                        fmaxf(redA[2][lane], redA[3][lane]));
  const float wS = __expf(mx - M);
  redB[s][lane] = Z * wS;
  for (int i = t; i < 64 * 68; i += 256) (&obuf[0][0])[i] = 0.f;
  __syncthreads();
  const float Zt = redB[0][lane] + redB[1][lane] + redB[2][lane] + redB[3][lane];
  for (int r = 0; r < 4; ++r) {
    if (s == r) {
#pragma unroll
      for (int o = 0; o < CO_; ++o) obuf[lane][o] += wS * oacc[o];
    }
    __syncthreads();
  }

  // epilogue: out = gamma * (h@beta) + v1
  const float gam = gamma_p[0];
  const float inv = 1.0f / Zt;
  const float* vb = v1 + (size_t)b * CO_ * L_ + m0;
  float* ob = out + (size_t)b * CO_ * L_ + m0;
#pragma unroll
  for (int i = 0; i < 16; ++i) {
    const int o = s * 16 + i;
    ob[(size_t)o * L_ + lane] =
        gam * obuf[lane][o] * inv + vb[(size_t)o * L_ + lane];
  }
}

extern "C" void kernel_launch(void* const* d_in, const int* in_sizes, int n_in,
                              void* d_out, int out_size, void* d_ws,
                              size_t ws_size, hipStream_t stream) {
  const float* x = (const float*)d_in[0];
  const float* Wq = (const float*)d_in[1];
  const float* Wk = (const float*)d_in[2];
  const float* Wv = (const float*)d_in[3];
  const float* Wv1 = (const float*)d_in[4];
  const float* gamma = (const float*)d_in[5];
  float* out = (float*)d_out;
  float* ws = (float*)d_ws;  // needs >= 16 MB (4 x 4 MB fp32 buffers)

  const dim3 grid(L_ / 64, B_);  // 64 x 4 = 256 blocks
  proj_kernel<<<grid, 256, 0, stream>>>(x, Wq, Wk, Wv, Wv1, ws);
  attn_kernel<<<grid, 256, 0, stream>>>(ws, gamma, out);
}

// Round 2
// 145.187 us; speedup vs baseline: 7.2649x; 7.2649x over previous
//
#include <hip/hip_runtime.h>
#include <math.h>

// Problem constants (fixed by the reference):
#define B_ 4
#define C_ 192
#define L_ 4096
#define CO_ 64

using half8 = __attribute__((ext_vector_type(8))) _Float16;
using half4v = __attribute__((ext_vector_type(4))) _Float16;
using half2v = __attribute__((ext_vector_type(2))) _Float16;
using f32x16 = __attribute__((ext_vector_type(16))) float;

// ---------------------------------------------------------------------------
// ws layout (all fully rewritten every call; 0xAA poison harmless):
//   Wf  : 4 * 64 * 192 f16          (98304 B)
//   fB  : [b][l][o]  f16  B*L*64    (2 MB)   A-operand for S   (f = Wq x)
//   gB  : [b][m][o]  f16  B*L*64    (2 MB)   B-operand for S   (g = Wk x)
//   hB  : [b][o][l]  f16  B*64*L    (2 MB)   A-operand for O   (h = Wv x)
//   v1N : [b][o][l]  f32  B*64*L    (4 MB)   epilogue add      (v1 = Wv1 x)
// total ~10.2 MB  (round-1 proved ws_size >= 16 MB)
// ---------------------------------------------------------------------------

// Kernel 0: convert the four weight matrices fp32 -> f16, contiguous copy.
__global__ void wcvt_kernel(const float* __restrict__ Wq,
                            const float* __restrict__ Wk,
                            const float* __restrict__ Wv,
                            const float* __restrict__ Wv1,
                            _Float16* __restrict__ Wf) {
  const float* src = (blockIdx.y == 0) ? Wq
                     : (blockIdx.y == 1) ? Wk
                     : (blockIdx.y == 2) ? Wv : Wv1;
  const int idx = (blockIdx.x * 256 + threadIdx.x) * 4;  // 12 blocks * 1024 = 12288
  if (idx < CO_ * C_) {
    const float4 v = *(const float4*)(src + idx);
    half4v h;
    h[0] = (_Float16)v.x; h[1] = (_Float16)v.y;
    h[2] = (_Float16)v.z; h[3] = (_Float16)v.w;
    *(half4v*)(Wf + (size_t)blockIdx.y * CO_ * C_ + idx) = h;
  }
}

// ---------------------------------------------------------------------------
// Kernel 1: projections via MFMA.  D[o][l] = sum_c W[o][c] x[c][l], K=192.
// Grid (L/64, B), 256 threads.  Wave w owns projection w; per wave 4
// 32x32 quadrants (o-half x l-half), 12 MFMA k-steps each.
// x tile staged in LDS as f16 [l][c] (stride 200 halfs, 16B-aligned rows).
// ---------------------------------------------------------------------------
__global__ __launch_bounds__(256) void proj_mfma(
    const float* __restrict__ x, const _Float16* __restrict__ Wf,
    _Float16* __restrict__ fB, _Float16* __restrict__ gB,
    _Float16* __restrict__ hB, float* __restrict__ v1N) {
  __shared__ __align__(16) _Float16 xT[64][200];
  const int b = blockIdx.y, l0 = blockIdx.x * 64;
  const int t = threadIdx.x;
  const int lane = t & 63, w = t >> 6;
  const int m = lane & 31, hi = lane >> 5;

  // stage x[b][c][l0..l0+64) -> xT[l][c] f16
  {
    const int l = t & 63, cq = t >> 6;
    const float* xb = x + (size_t)b * C_ * L_ + l0 + l;
#pragma unroll
    for (int i = 0; i < 24; ++i) {
      const int c0 = 2 * (cq + 4 * i);
      const float a0 = xb[(size_t)c0 * L_];
      const float a1 = xb[(size_t)(c0 + 1) * L_];
      half2v h; h[0] = (_Float16)a0; h[1] = (_Float16)a1;
      *(half2v*)&xT[l][c0] = h;
    }
  }
  __syncthreads();

  const _Float16* Wp = Wf + (size_t)w * CO_ * C_;
  for (int oh = 0; oh < 2; ++oh) {
    for (int lh = 0; lh < 2; ++lh) {
      f32x16 acc = {};
#pragma unroll
      for (int ks = 0; ks < 12; ++ks) {
        const half8 aF =
            *(const half8*)(Wp + (size_t)(32 * oh + m) * C_ + ks * 16 + hi * 8);
        const half8 bF = *(const half8*)&xT[32 * lh + m][ks * 16 + hi * 8];
        acc = __builtin_amdgcn_mfma_f32_32x32x16_f16(aF, bF, acc, 0, 0, 0);
      }
      const int lg = l0 + 32 * lh + m;  // global column (l) this lane owns
      if (w < 2) {
        // fB/gB: [b][l][o] f16 — lane writes its row, o pairs packed
        _Float16* dst = (w == 0 ? fB : gB) + ((size_t)b * L_ + lg) * CO_;
#pragma unroll
        for (int r = 0; r < 16; r += 2) {
          const int o = 32 * oh + 4 * hi + 8 * (r >> 2) + (r & 3);
          half2v h; h[0] = (_Float16)acc[r]; h[1] = (_Float16)acc[r + 1];
          *(half2v*)(dst + o) = h;
        }
      } else if (w == 2) {
        // hB: [b][o][l] f16 — lanes are consecutive l -> coalesced 2B stores
#pragma unroll
        for (int r = 0; r < 16; ++r) {
          const int o = 32 * oh + 4 * hi + 8 * (r >> 2) + (r & 3);
          hB[((size_t)b * CO_ + o) * L_ + lg] = (_Float16)acc[r];
        }
      } else {
        // v1N: [b][o][l] f32 — coalesced dword stores
#pragma unroll
        for (int r = 0; r < 16; ++r) {
          const int o = 32 * oh + 4 * hi + 8 * (r >> 2) + (r & 3);
          v1N[((size_t)b * CO_ + o) * L_ + lg] = acc[r];
        }
      }
    }
  }
}

// ---------------------------------------------------------------------------
// Kernel 2: flash attention, f16 MFMA.
// Grid (L/32 m-tiles, B) = 512 blocks, 256 threads = 4 waves.
// Wave s owns l-partition [s*1024, (s+1)*1024), 32 steps of 32 l.
// Per step: S[l][m] (32x32, k=o=64, 4 MFMA) -> per-lane online softmax
// (col = m = lane&31 -> scalar mx/Z per lane; row-l reduce = 15 v_max +
// shfl_xor(32)) -> P through per-wave LDS (C-layout -> B-operand layout)
// -> O[o][m] += h P (4 MFMA, 2 o-halves x 2 k-steps).  No barriers in loop.
// End: merge the 4 l-partitions via LDS, epilogue adds gamma/Z and v1.
// ---------------------------------------------------------------------------
__global__ __launch_bounds__(256) void attn_mfma(
    const _Float16* __restrict__ fB, const _Float16* __restrict__ gB,
    const _Float16* __restrict__ hB, const float* __restrict__ v1N,
    const float* __restrict__ gamma_p, float* __restrict__ out) {
  __shared__ __align__(16) _Float16 Pl[4][32 * 40];  // per-wave P, stride 40
  __shared__ float obuf[64][33];
  __shared__ float redM[4][32];
  __shared__ float redZ[4][32];

  const int b = blockIdx.y, m0 = blockIdx.x * 32;
  const int t = threadIdx.x;
  const int lane = t & 63, s = t >> 6;
  const int m = lane & 31, hi = lane >> 5;

  // loop-invariant g B-frags: B[k=o][n=m], n = lane&31
  const _Float16* gRow = gB + ((size_t)b * L_ + m0 + m) * CO_;
  half8 gf[4];
#pragma unroll
  for (int ks = 0; ks < 4; ++ks)
    gf[ks] = *(const half8*)(gRow + ks * 16 + hi * 8);

  const _Float16* fBase = fB + (size_t)b * L_ * CO_;
  const _Float16* hBase = hB + (size_t)b * CO_ * L_;
  _Float16* Pw = &Pl[s][0];

  f32x16 o0 = {}, o1 = {};
  float mx = -INFINITY, Z = 0.f;

  for (int stp = 0; stp < 32; ++stp) {
    const int lb = s * 1024 + stp * 32;
    // S = f^T g : A[l][k=o] from fB, rows l = lane&31
    f32x16 S = {};
#pragma unroll
    for (int ks = 0; ks < 4; ++ks) {
      const half8 aF =
          *(const half8*)(fBase + (size_t)(lb + m) * CO_ + ks * 16 + hi * 8);
      S = __builtin_amdgcn_mfma_f32_32x32x16_f16(aF, gf[ks], S, 0, 0, 0);
    }
    // online softmax over l (rows): in-lane over 16 regs + partner lane^32
    float tmax = S[0];
#pragma unroll
    for (int r = 1; r < 16; ++r) tmax = fmaxf(tmax, S[r]);
    tmax = fmaxf(tmax, __shfl_xor(tmax, 32, 64));
    const float mnew = fmaxf(mx, tmax);
    const float corr = __expf(mx - mnew);  // exp(-inf)=0 on first step
    mx = mnew;
    float p[16];
    float zl = 0.f;
#pragma unroll
    for (int r = 0; r < 16; ++r) {
      p[r] = __expf(S[r] - mx);
      zl += p[r];
    }
    zl += __shfl_xor(zl, 32, 64);  // symmetric: pair stays bit-identical
    Z = Z * corr + zl;
#pragma unroll
    for (int r = 0; r < 16; ++r) { o0[r] *= corr; o1[r] *= corr; }
    // P (C-layout) -> LDS [m][l] f16, stride 40 halfs
#pragma unroll
    for (int r = 0; r < 16; r += 2) {
      const int ll = 4 * hi + 8 * (r >> 2) + (r & 3);
      half2v hp; hp[0] = (_Float16)p[r]; hp[1] = (_Float16)p[r + 1];
      *(half2v*)(Pw + m * 40 + ll) = hp;
    }
    // O += h P : A[o][k=l] from hB, B[k=l][n=m] from LDS
#pragma unroll
    for (int ks = 0; ks < 2; ++ks) {
      const half8 bP = *(const half8*)(Pw + m * 40 + ks * 16 + hi * 8);
      const half8 a0 =
          *(const half8*)(hBase + (size_t)m * L_ + lb + ks * 16 + hi * 8);
      const half8 a1 =
          *(const half8*)(hBase + (size_t)(32 + m) * L_ + lb + ks * 16 + hi * 8);
      o0 = __builtin_amdgcn_mfma_f32_32x32x16_f16(a0, bP, o0, 0, 0, 0);
      o1 = __builtin_amdgcn_mfma_f32_32x32x16_f16(a1, bP, o1, 0, 0, 0);
    }
  }

  // ---- merge the 4 l-partitions ----
  redM[s][m] = mx;  // hi pair writes identical value
  __syncthreads();
  const float M = fmaxf(fmaxf(redM[0][m], redM[1][m]),
                        fmaxf(redM[2][m], redM[3][m]));
  const float sc = __expf(mx - M);
  redZ[s][m] = Z * sc;
  for (int i = t; i < 64 * 33; i += 256) (&obuf[0][0])[i] = 0.f;
  __syncthreads();
  const float Zt = redZ[0][m] + redZ[1][m] + redZ[2][m] + redZ[3][m];
  for (int r0 = 0; r0 < 4; ++r0) {
    if (s == r0) {
#pragma unroll
      for (int r = 0; r < 16; ++r) {
        const int o = 4 * hi + 8 * (r >> 2) + (r & 3);
        obuf[o][m] += sc * o0[r];
        obuf[o + 32][m] += sc * o1[r];
      }
    }
    __syncthreads();
  }

  // epilogue: out[b][o][m0+m] = gamma * obuf[o][m]/Zt + v1
  const float gam = gamma_p[0];
  const float inv = 1.0f / Zt;  // Zt is for m = lane&31 = t&31
  const int og = t >> 5;        // 0..7
  const int me = t & 31;
#pragma unroll
  for (int i = 0; i < 8; ++i) {
    const int o = og * 8 + i;
    const size_t gidx = ((size_t)b * CO_ + o) * L_ + m0 + me;
    out[gidx] = gam * obuf[o][me] * inv + v1N[gidx];
  }
}

extern "C" void kernel_launch(void* const* d_in, const int* in_sizes, int n_in,
                              void* d_out, int out_size, void* d_ws,
                              size_t ws_size, hipStream_t stream) {
  const float* x = (const float*)d_in[0];
  const float* Wq = (const float*)d_in[1];
  const float* Wk = (const float*)d_in[2];
  const float* Wv = (const float*)d_in[3];
  const float* Wv1 = (const float*)d_in[4];
  const float* gamma = (const float*)d_in[5];
  float* out = (float*)d_out;

  _Float16* Wf = (_Float16*)d_ws;                       // 4*64*192
  _Float16* fB = Wf + (size_t)4 * CO_ * C_;             // B*L*64 f16
  _Float16* gB = fB + (size_t)B_ * L_ * CO_;
  _Float16* hB = gB + (size_t)B_ * L_ * CO_;
  float* v1N = (float*)(hB + (size_t)B_ * L_ * CO_);    // B*64*L f32

  wcvt_kernel<<<dim3(12, 4), 256, 0, stream>>>(Wq, Wk, Wv, Wv1, Wf);
  proj_mfma<<<dim3(L_ / 64, B_), 256, 0, stream>>>(x, Wf, fB, gB, hB, v1N);
  attn_mfma<<<dim3(L_ / 32, B_), 256, 0, stream>>>(fB, gB, hB, v1N, gamma, out);
}